// Round 11
// baseline (308.135 us; speedup 1.0000x reference)
//
#include <hip/hip_runtime.h>
#include <hip/hip_bf16.h>
#include <math.h>

// ---------- types ----------
typedef __attribute__((ext_vector_type(8))) __bf16 bf16x8;
typedef __attribute__((ext_vector_type(4))) float f32x4;

// fp32 -> bf16 round-to-nearest-even
__device__ __forceinline__ unsigned short f2bf(float f) {
    union { float f; unsigned u; } v; v.f = f;
    unsigned r = v.u + 0x7fffu + ((v.u >> 16) & 1u);
    return (unsigned short)(r >> 16);
}
// pack two fp32 into one dword of two bf16 (lo, hi)
__device__ __forceinline__ unsigned int pk(float a, float b) {
    union { float f; unsigned u; } x, y; x.f = a; y.f = b;
    unsigned ra = (x.u + 0x7fffu + ((x.u >> 16) & 1u)) >> 16;
    unsigned rb = (y.u + 0x7fffu + ((y.u >> 16) & 1u)) & 0xffff0000u;
    return ra | rb;
}

// ---------- weight kernel ----------
// 448 blocks: convert W to MFMA FRAGMENT ORDER (round-8 layout):
//   WTf[kt][cg][lane][e]; B load in GEMM = base + lane*16, coalesced 1 KB.
// Runs as its own kernel; stream order guarantees completion before fused.
struct WArgs {
    const float* W[5];
    unsigned short* WT[5];
    int N[5];
    int tstart[6];
};

__global__ __launch_bounds__(256) void wprep_kernel(WArgs a) {
    __shared__ float tile[64][65];
    const int blk = blockIdx.x;
    const int tid = threadIdx.x;
    int m = 0;
    while (blk >= a.tstart[m + 1]) m++;
    const float* src = a.W[m];
    unsigned short* dst = a.WT[m];
    const int N = a.N[m];
    const int t = blk - a.tstart[m];
    const int ntn = N >> 6;
    const int tk = t / ntn, tn = t % ntn;
    const int c = tid & 63, r0 = tid >> 6;
    #pragma unroll
    for (int r = r0; r < 64; r += 4)
        tile[r][c] = src[(size_t)(tk * 64 + r) * N + tn * 64 + c];
    __syncthreads();
    const int l = tid & 63;
    #pragma unroll
    for (int fi = tid >> 6; fi < 8; fi += 4) {
        const int ktl = fi & 1, cgl = fi >> 1;
        const int kt = tk * 2 + ktl, cg = tn * 4 + cgl;
        const int kb = ktl * 32 + (l >> 4) * 8;
        const int nb = cgl * 16 + (l & 15);
        uint4 o;
        o.x = pk(tile[kb + 0][nb], tile[kb + 1][nb]);
        o.y = pk(tile[kb + 2][nb], tile[kb + 3][nb]);
        o.z = pk(tile[kb + 4][nb], tile[kb + 5][nb]);
        o.w = pk(tile[kb + 6][nb], tile[kb + 7][nb]);
        ((uint4*)dst)[((size_t)kt * 32 + cg) * 64 + l] = o;
    }
}

// ---------- fused two-layer GEMM, A DIRECT FROM fv ----------
// ROUND-11 STRUCTURE: the prep pass (fv->bf16 intermediate) is DELETED.
// Register-staged A lifts the gl2lds wave-uniform-dest constraint, so fused
// reads fv (fp32) directly: thread (r=tid>>3, ks=tid&7) loads one float4 of
// row m0+r at k = h*32 + ks*4, converts (pk), ds_writes 8 B into the
// chunk-XOR-swizzled As layout (slot (ks>>1)^(r&3), half ks&1).  Saves
// ~110 MB of At round-trip + a full kernel pass + launch gap.
// All VMEM is now reg-destined -> COMPILER tracks every wait (no manual
// vmcnt proof).  Per-step sync is only: s_waitcnt lgkmcnt(0); s_barrier.
//   RAW: my ds_writes for buf X at step h are lgkm-drained before barrier
//     h+1; readers read X at h+1 after that barrier.
//   WAR: my ds_write to buf (h+1)&1 at step h happens after barrier h;
//     the other waves' reads of that buffer (step h-1) completed before
//     their MMAC(h-1) lgkm-wait, which precedes their barrier-h arrival.
// Pipeline: loads 2 steps ahead (va/vb alternate, loop unrolled 2x for
// static reg naming -- rule 20); MMAC(h)'s implicit wait on B(h) retires
// load(h+1) (issued one step earlier), so the ds_write after MMAC never
// stalls; load(h+2) stays in flight across the barrier.
// Block: BM=64 rows x ALL 512 cols, 8 waves, wave owns 64 cols: acc[4][4].
// hid LDS [64][512] bf16, 16B-chunk XOR swizzle -> L2-stage reads 2-way max.
// PATH 0: relu->hid(LDS)->L2->out fp32 (+bias), rows m=b*P+p, q=QBASE+p
// PATH 2: single layer, tanh->out, rows m=b*8+i, q=qmap[i]
#define LOADB(DST, WTP, K0)                                                  \
    _Pragma("unroll") for (int ni = 0; ni < 4; ni++)                         \
        DST[ni] = *(const bf16x8*)((WTP) +                                   \
            ((((size_t)(K0) >> 5) * 32 + cg0 + ni) << 9) + (lane << 3));

#define MMAC(BF, AF)                                                         \
    _Pragma("unroll") for (int mi = 0; mi < 4; mi++)                         \
    _Pragma("unroll") for (int ni = 0; ni < 4; ni++)                         \
        acc[mi][ni] = __builtin_amdgcn_mfma_f32_16x16x32_bf16(               \
            AF[mi], BF[ni], acc[mi][ni], 0, 0, 0);

#define LBAR()                                                               \
    asm volatile("s_waitcnt lgkmcnt(0)" ::: "memory");                       \
    asm volatile("s_barrier" ::: "memory");

template <int P, int K1, int PATH, int QBASE>
__device__ __forceinline__ void fused_seg(
    const float* __restrict__ fv,
    const int* __restrict__ idx,
    const unsigned short* __restrict__ W1T,
    const float* __restrict__ b1,
    const unsigned short* __restrict__ W2T,
    const float* __restrict__ b2,
    float* __restrict__ out,
    const int* __restrict__ leftover,
    int local,
    unsigned short* As, unsigned short* hid) {

    const int tid  = threadIdx.x;
    const int lane = tid & 63, w = tid >> 6;      // 8 waves
    const int ln15 = lane & 15;
    const int kq   = lane >> 4;                   // k-chunk quad 0..3
    const int wn   = w * 64;                      // wave's col base
    const int cg0  = w * 4;                       // wave's col-group base
    const int m0   = local * 64;                  // block's row base
    constexpr int NTK = K1 / 32;                  // 32 or 16 (even)

    // --- A staging geometry: thread covers row r, k-segment ks (4 floats)
    const int r  = tid >> 3;                      // 0..63
    const int ks = tid & 7;                       // 0..7
    const float *ar0, *ar1;
    {
        const int m = m0 + r;
        if constexpr (PATH == 0) {
            const int b = m / P, p = m % P;
            ar0 = fv + ((size_t)b * 64 + idx[2 * p]) * 512 + ks * 4;
            ar1 = fv + ((size_t)b * 64 + idx[2 * p + 1]) * 512 + ks * 4;
        } else {
            const int b = m >> 3, i = m & 7;
            ar0 = fv + ((size_t)b * 64 + idx[i]) * 512 + ks * 4;
            ar1 = ar0;
        }
    }
    auto ldA = [&](int t) -> float4 {
        const int k0 = t * 32;
        if constexpr (K1 == 1024)
            return *(const float4*)(k0 >= 512 ? ar1 + (k0 - 512) : ar0 + k0);
        else
            return *(const float4*)(ar0 + k0);
    };
    // ds_write dest (shorts): row r, chunk slot (ks>>1)^(r&3), half ks&1
    unsigned short* const wdst =
        As + r * 32 + (((ks >> 1) ^ (r & 3)) << 3) + ((ks & 1) << 2);
    auto wrA = [&](int buf, float4 v) {
        uint2 o; o.x = pk(v.x, v.y); o.y = pk(v.z, v.w);
        *(uint2*)(wdst + buf * 2048) = o;
    };
    const int xsel = (kq ^ (lane & 3)) * 8;       // frag-read chunk slot

    f32x4 acc[4][4];
    #pragma unroll
    for (int mi = 0; mi < 4; mi++)
        #pragma unroll
        for (int ni = 0; ni < 4; ni++)
            acc[mi][ni] = f32x4{0.f, 0.f, 0.f, 0.f};

    bf16x8 bA[4];

    // ---- L1: acc = A[64,K1] @ W1[K1,512] ----
    float4 va = ldA(0);
    float4 vb = ldA(1);
    wrA(0, va);                    // compiler waits va's load
    LBAR();                        // buf0 visible to all waves

    for (int h = 0; h < NTK; h += 2) {
        // even step: read buf0, write buf1 (data vb = load(h+1))
        {
            LOADB(bA, W1T, h * 32);
            if (h + 2 < NTK) va = ldA(h + 2);
            bf16x8 af[4];
            #pragma unroll
            for (int mi = 0; mi < 4; mi++)
                af[mi] = *(const bf16x8*)&As[(mi * 16 + ln15) * 32 + xsel];
            MMAC(bA, af);                      // waits B(h); retires load(h+1)
            wrA(1, vb);
            LBAR();
        }
        // odd step: read buf1, write buf0 (data va = load(h+2))
        {
            LOADB(bA, W1T, (h + 1) * 32);
            if (h + 3 < NTK) vb = ldA(h + 3);
            bf16x8 af[4];
            #pragma unroll
            for (int mi = 0; mi < 4; mi++)
                af[mi] = *(const bf16x8*)&As[2048 + (mi * 16 + ln15) * 32 + xsel];
            MMAC(bA, af);                      // waits B(h+1); retires load(h+2)
            if (h + 2 < NTK) { wrA(0, va); }
            LBAR();
        }
    }

    if constexpr (PATH == 2) {
        // single layer: tanh -> out at leftover slot
        int qmap[8];
        #pragma unroll
        for (int i = 0; i < 8; i++) {
            const int f = idx[i];
            int q = 24;
            for (int l = 0; l < 16; l++)
                if (leftover[l] == f) q = 24 + l;
            qmap[i] = q;
        }
        #pragma unroll
        for (int ni = 0; ni < 4; ni++) {
            const int n = wn + ni * 16 + ln15;
            const float bv = b1[n];
            #pragma unroll
            for (int mi = 0; mi < 4; mi++)
                #pragma unroll
                for (int j = 0; j < 4; j++) {
                    const int rr = mi * 16 + kq * 4 + j;
                    const int m = m0 + rr;
                    const int b = m >> 3, i = m & 7;
                    out[((size_t)b * 40 + qmap[i]) * 512 + n] =
                        tanhf(acc[mi][ni][j] + bv);
                }
        }
        return;
    }

    // ---- L1 epilogue: relu -> bf16 -> hid LDS (XOR-swizzled chunks) ----
    #pragma unroll
    for (int ni = 0; ni < 4; ni++) {
        const int n  = wn + ni * 16 + ln15;
        const float bv = b1[n];
        const int c8 = n >> 3;
        const int cl = (n & 7) * 2;
        #pragma unroll
        for (int mi = 0; mi < 4; mi++)
            #pragma unroll
            for (int j = 0; j < 4; j++) {
                const int rr = mi * 16 + kq * 4 + j;
                float v = acc[mi][ni][j] + bv;
                v = v > 0.f ? v : 0.f;
                *(unsigned short*)((char*)hid + rr * 1024 +
                                   ((c8 ^ (rr & 7)) * 16) + cl) = f2bf(v);
            }
    }
    #pragma unroll
    for (int mi = 0; mi < 4; mi++)
        #pragma unroll
        for (int ni = 0; ni < 4; ni++)
            acc[mi][ni] = f32x4{0.f, 0.f, 0.f, 0.f};
    __syncthreads();                       // hid visible

    // ---- L2: acc = hid[64,512] @ W2[512,512], A from LDS, no barriers ----
    for (int t2 = 0; t2 < 16; t2++) {
        LOADB(bA, W2T, t2 * 32);
        bf16x8 af[4];
        #pragma unroll
        for (int mi = 0; mi < 4; mi++) {
            const int rr = mi * 16 + ln15;
            const int c8 = t2 * 4 + kq;
            af[mi] = *(const bf16x8*)((char*)hid + rr * 1024 +
                                      ((c8 ^ (rr & 7)) * 16));
        }
        MMAC(bA, af);
    }

    // ---- L2 epilogue: +bias -> fp32 out ----
    #pragma unroll
    for (int ni = 0; ni < 4; ni++) {
        const int n  = wn + ni * 16 + ln15;
        const float bv = b2[n];
        #pragma unroll
        for (int mi = 0; mi < 4; mi++)
            #pragma unroll
            for (int j = 0; j < 4; j++) {
                const int rr = mi * 16 + kq * 4 + j;
                const int m = m0 + rr;
                const int b = m / P, p = m % P;    // P constexpr -> shifts
                out[((size_t)b * 40 + QBASE + p) * 512 + n] =
                    acc[mi][ni][j] + bv;
            }
    }
}

// ---------- fused phase kernel (GEMM blocks + leftover-copy blocks) ----------
struct FArgs {
    const float* fv;
    const unsigned short *and_W1T, *and_W2T, *or_W1T, *or_W2T, *not_WT;
    const int *and_pairs, *or_pairs, *not_idx, *leftover;
    const float *and_b1, *and_b2, *or_b1, *or_b2, *not_b;
    float* out;
};

__global__ __launch_bounds__(512, 4) void fused_phase(FArgs a) {
    __shared__ __align__(16) unsigned short As[2 * 64 * 32];   // 8 KB, 2 bufs
    __shared__ __align__(16) unsigned short hid[64 * 512];     // 64 KB
    const int blk = blockIdx.x;
    if (blk < 256) {      // and: M=16384 -> 256 blocks of 64 rows
        fused_seg<16, 1024, 0, 0>(a.fv, a.and_pairs, a.and_W1T, a.and_b1,
                                  a.and_W2T, a.and_b2, a.out, nullptr,
                                  blk, As, hid);
    } else if (blk < 384) { // or: M=8192 -> 128 blocks
        fused_seg<8, 1024, 0, 16>(a.fv, a.or_pairs, a.or_W1T, a.or_b1,
                                  a.or_W2T, a.or_b2, a.out, nullptr,
                                  blk - 256, As, hid);
    } else if (blk < 512) { // not: M=8192, single layer tanh -> 128 blocks
        fused_seg<8, 512, 2, 24>(a.fv, a.not_idx, a.not_WT, a.not_b,
                                 nullptr, nullptr, a.out, a.leftover,
                                 blk - 384, As, hid);
    } else {
        // leftover passthrough: slot ls in 0..15, skip not-slots (tanh
        // path writes those).  One wave = one (b,ls) row of 512 floats.
        const int t = (blk - 512) * 512 + threadIdx.x;   // 8 floats each
        const size_t e = (size_t)t * 8;
        const int c  = (int)(e & 511);
        const int ls = (int)((e >> 9) & 15);
        const int b  = (int)(e >> 13);
        const int f  = a.leftover[ls];                   // wave-uniform
        int isnot = 0;
        #pragma unroll
        for (int i = 0; i < 8; i++) isnot |= (a.not_idx[i] == f);
        if (isnot) return;
        const float* s = a.fv + ((size_t)b * 64 + f) * 512 + c;
        float* d = a.out + ((size_t)b * 40 + 24 + ls) * 512 + c;
        *(float4*)(d)     = *(const float4*)(s);
        *(float4*)(d + 4) = *(const float4*)(s + 4);
    }
}

// ---------- launch ----------
extern "C" void kernel_launch(void* const* d_in, const int* in_sizes, int n_in,
                              void* d_out, int out_size, void* d_ws, size_t ws_size,
                              hipStream_t stream) {
    const float* fv       = (const float*)d_in[0];
    const float* and_W1   = (const float*)d_in[1];
    const float* and_b1   = (const float*)d_in[2];
    const float* and_W2   = (const float*)d_in[3];
    const float* and_b2   = (const float*)d_in[4];
    const float* or_W1    = (const float*)d_in[5];
    const float* or_b1    = (const float*)d_in[6];
    const float* or_W2    = (const float*)d_in[7];
    const float* or_b2    = (const float*)d_in[8];
    const float* not_W    = (const float*)d_in[9];
    const float* not_b    = (const float*)d_in[10];
    const int* not_idx    = (const int*)d_in[11];
    const int* and_pairs  = (const int*)d_in[12];
    const int* or_pairs   = (const int*)d_in[13];
    const int* leftover   = (const int*)d_in[14];
    float* out = (float*)d_out;
    char* ws = (char*)d_ws;

    // ws layout (bytes) -- weights only now
    unsigned short* and_W1T = (unsigned short*)(ws);              // 1 MB
    unsigned short* or_W1T  = (unsigned short*)(ws + 1048576);    // 1 MB
    unsigned short* and_W2T = (unsigned short*)(ws + 2097152);    // 0.5 MB
    unsigned short* or_W2T  = (unsigned short*)(ws + 2621440);    // 0.5 MB
    unsigned short* not_WT  = (unsigned short*)(ws + 3145728);    // 0.5 MB

    WArgs wa;
    wa.W[0] = and_W1; wa.WT[0] = and_W1T; wa.N[0] = 512;
    wa.W[1] = or_W1;  wa.WT[1] = or_W1T;  wa.N[1] = 512;
    wa.W[2] = and_W2; wa.WT[2] = and_W2T; wa.N[2] = 512;
    wa.W[3] = or_W2;  wa.WT[3] = or_W2T;  wa.N[3] = 512;
    wa.W[4] = not_W;  wa.WT[4] = not_WT;  wa.N[4] = 512;
    wa.tstart[0] = 0;   wa.tstart[1] = 128; wa.tstart[2] = 256;
    wa.tstart[3] = 320; wa.tstart[4] = 384; wa.tstart[5] = 448;
    wprep_kernel<<<dim3(448), dim3(256), 0, stream>>>(wa);

    FArgs fa;
    fa.fv = fv;
    fa.and_W1T = and_W1T; fa.and_W2T = and_W2T;
    fa.or_W1T = or_W1T;   fa.or_W2T = or_W2T;   fa.not_WT = not_WT;
    fa.and_pairs = and_pairs; fa.or_pairs = or_pairs; fa.not_idx = not_idx;
    fa.leftover = leftover;
    fa.and_b1 = and_b1; fa.and_b2 = and_b2;
    fa.or_b1 = or_b1;   fa.or_b2 = or_b2;   fa.not_b = not_b;
    fa.out = out;
    // 512 GEMM blocks + 2048 leftover-copy blocks (16 slots x 1024 b x 512
    // floats / (512 thr x 8 floats)); GEMM first (longest -> scheduled first)
    fused_phase<<<dim3(512 + 2048), dim3(512), 0, stream>>>(fa);
}